// Round 11
// baseline (111.713 us; speedup 1.0000x reference)
//
#include <hip/hip_runtime.h>
#include <stdint.h>
#include <stddef.h>

#define SEQ   2048
#define HD    64
#define DM    1024
#define NHEAD 16

typedef __bf16 bf16x8 __attribute__((ext_vector_type(8)));
typedef __bf16 bf16x4 __attribute__((ext_vector_type(4)));
typedef float  f32x4  __attribute__((ext_vector_type(4)));

#define MFMA16x16(a, b, c) __builtin_amdgcn_mfma_f32_16x16x32_bf16((a), (b), (c), 0, 0, 0)

__device__ __forceinline__ void gload16(const void* g, void* lds_uniform) {
    __builtin_amdgcn_global_load_lds(
        (const __attribute__((address_space(1))) uint32_t*)g,
        (__attribute__((address_space(3))) uint32_t*)lds_uniform, 16, 0, 0);
}

// ---------------- prep: fp32->bf16 for x + 4 weights, and rope tables, ONE launch ----
__global__ void prep_kernel(const float* __restrict__ x,
                            const float* __restrict__ wq, const float* __restrict__ wk,
                            const float* __restrict__ wv, const float* __restrict__ wo,
                            __bf16* __restrict__ xb, __bf16* __restrict__ wqkv,
                            __bf16* __restrict__ wob,
                            float* __restrict__ ct, float* __restrict__ st) {
    int bid = blockIdx.x;
    if (bid < 4096) {                       // x: 4M elements
        int i = (bid * 256 + threadIdx.x) * 4;
        const float4 v = *(const float4*)(x + i);
        __bf16 o[4] = {(__bf16)v.x, (__bf16)v.y, (__bf16)v.z, (__bf16)v.w};
        *(uint64_t*)(xb + i) = *(const uint64_t*)o;
    } else if (bid < 8192) {                // weights: 4 x 1M elements
        int g = (bid - 4096) >> 10;
        int i = (((bid - 4096) & 1023) * 256 + threadIdx.x) * 4;
        const float* src = (g == 0) ? wq : (g == 1) ? wk : (g == 2) ? wv : wo;
        __bf16* dst = (g == 3) ? wob : (wqkv + (size_t)g * 1048576);
        const float4 v = *(const float4*)(src + i);
        __bf16 o[4] = {(__bf16)v.x, (__bf16)v.y, (__bf16)v.z, (__bf16)v.w};
        *(uint64_t*)(dst + i) = *(const uint64_t*)o;
    } else {                                // rope tables: 65536 entries
        int i = (bid - 8192) * 256 + threadIdx.x;
        int p = i & 31;
        int pos = i >> 5;
        float freq = expf(-(float)p * (logf(10000.0f) / 32.0f));  // theta^(-p/32)
        float ang = (float)pos * freq;
        ct[i] = cosf(ang);
        st[i] = sinf(ang);
    }
}

// ---------------- GEMM: C[m][n] = sum_k A[m][k] * W[n][k]  (both K-contiguous) --------
// 128(M)xBN(N) tile, BK=64, 4 waves (2x2, each 64 x BN/2), global_load_lds(16B)
// staging with pre-swizzled source; LDS rows 128B, chunk XOR swizzle.
// Linear grid, XCD-chunked (grid divisible by 8 -> bijective).
// MODE 0 (BN=128): N=3072 QKV; epilogue scatters bf16 to Q/K[B,H,L,64], VT[B,H,64,L]
//         via per-wave LDS transpose tile; RoPE fused (Q gets 0.125*log2e scale).
// MODE 1 (BN=64): plain fp32 C output; 512 blocks -> 2 blocks/CU.
template <int MODE, int BN>
__global__ __launch_bounds__(256, 4)
void gemm_bt_kernel(const __bf16* __restrict__ A, const __bf16* __restrict__ W,
                    float* __restrict__ C, __bf16* __restrict__ Qb,
                    __bf16* __restrict__ Kb, __bf16* __restrict__ VTb,
                    const int* __restrict__ tpos, const float* __restrict__ ct,
                    const float* __restrict__ st, int N, int K) {
    constexpr int NJ = BN >> 5;           // n-subtiles per wave / B staging rounds
    __shared__ __align__(16) char smem[16384 + BN * 128];
    char* As = smem;
    char* Bs = smem + 16384;
    const int lane = threadIdx.x & 63;
    const int w    = threadIdx.x >> 6;

    const int nbn = N / BN;               // blocks along n
    const int per = (nbn * 32) >> 3;      // blocks per XCD (grid divisible by 8)
    const int id  = blockIdx.x;
    const int lin = (id & 7) * per + (id >> 3);
    const int bm  = lin / nbn;            // bm-major within the XCD chunk
    const int bn  = lin % nbn;

    const int rbase = (w >> 1) * 64;
    const int cbase = (w & 1) * (BN / 2);

    f32x4 acc[4][NJ] = {};

    const int kt_iters = K >> 6;
    for (int kt = 0; kt < kt_iters; ++kt) {
        #pragma unroll
        for (int c = 0; c < 4; ++c) {     // A: 128 rows
            int id2 = (c * 4 + w) * 64 + lane;
            int row = id2 >> 3, cc = id2 & 7;
            int koff = kt * 64 + ((cc ^ (row & 7)) << 3);
            gload16(A + (size_t)(bm * 128 + row) * K + koff, As + (c * 4 + w) * 1024);
        }
        #pragma unroll
        for (int c = 0; c < NJ; ++c) {    // B: BN rows
            int id2 = (c * 4 + w) * 64 + lane;
            int row = id2 >> 3, cc = id2 & 7;
            int koff = kt * 64 + ((cc ^ (row & 7)) << 3);
            gload16(W + (size_t)(bn * BN + row) * K + koff, Bs + (c * 4 + w) * 1024);
        }
        __syncthreads();
        #pragma unroll
        for (int ks = 0; ks < 2; ++ks) {
            bf16x8 af[4], bfr[NJ];
            #pragma unroll
            for (int i = 0; i < 4; ++i) {
                int row = rbase + i * 16 + (lane & 15);
                int c = ks * 4 + (lane >> 4);
                af[i] = *(const bf16x8*)(As + row * 128 + ((c ^ (row & 7)) << 4));
            }
            #pragma unroll
            for (int j = 0; j < NJ; ++j) {
                int row = cbase + j * 16 + (lane & 15);
                int c = ks * 4 + (lane >> 4);
                bfr[j] = *(const bf16x8*)(Bs + row * 128 + ((c ^ (row & 7)) << 4));
            }
            #pragma unroll
            for (int i = 0; i < 4; ++i)
                #pragma unroll
                for (int j = 0; j < NJ; ++j)
                    acc[i][j] = MFMA16x16(af[i], bfr[j], acc[i][j]);
        }
        __syncthreads();
    }

    if (MODE == 1) {
        #pragma unroll
        for (int i = 0; i < 4; ++i)
            #pragma unroll
            for (int j = 0; j < NJ; ++j)
                #pragma unroll
                for (int r = 0; r < 4; ++r) {
                    int m = bm * 128 + rbase + i * 16 + (lane >> 4) * 4 + r;
                    int n = bn * BN + cbase + j * 16 + (lane & 15);
                    C[(size_t)m * N + n] = acc[i][j][r];
                }
    } else {
        const int which = bn >> 3;    // 0=Q 1=K 2=V (128-col block never crosses)
        char* T = smem + w * 8192;    // per-wave 64x64 bf16, swizzled
        #pragma unroll
        for (int i = 0; i < 4; ++i)
            #pragma unroll
            for (int j = 0; j < NJ; ++j)
                #pragma unroll
                for (int r = 0; r < 4; ++r) {
                    int mi = i * 16 + (lane >> 4) * 4 + r;
                    int ni = j * 16 + (lane & 15);
                    __bf16 v = (__bf16)acc[i][j][r];
                    if (which == 2)
                        *(__bf16*)(T + ni * 128 + ((mi * 2) ^ ((ni & 7) << 4))) = v;
                    else
                        *(__bf16*)(T + mi * 128 + ((ni * 2) ^ ((mi & 7) << 4))) = v;
                }
        #pragma unroll
        for (int it = 0; it < 8; ++it) {
            int id2 = it * 64 + lane;
            int row = id2 >> 3, cc = id2 & 7;
            bf16x8 v = *(const bf16x8*)(T + row * 128 + ((cc ^ (row & 7)) << 4));
            if (which == 2) {
                int n = bn * BN + cbase + row;        // d-major row
                int m = bm * 128 + rbase + cc * 8;    // 8 consecutive l
                int b = m >> 11, l = m & (SEQ - 1);
                int h = (n & (DM - 1)) >> 6, d = n & 63;
                *(bf16x8*)(VTb + ((size_t)((b * NHEAD + h) * HD + d) * SEQ) + l) = v;
            } else {
                int m = bm * 128 + rbase + row;
                int n = bn * BN + cbase + cc * 8;     // 8 consecutive d
                int b = m >> 11, l = m & (SEQ - 1);
                int h = (n & (DM - 1)) >> 6, d = n & 63;
                // fused RoPE (pairs are even/odd within the 8 consecutive d)
                int pb = tpos[l] * 32 + (d >> 1);
                // Q: fold 1/sqrt(64) * log2(e) so softmax can use exp2
                float sc = (which == 0) ? 0.18033688011112042f : 1.0f;
                bf16x8 ov;
                #pragma unroll
                for (int jj = 0; jj < 4; ++jj) {
                    float cs = ct[pb + jj], sn = st[pb + jj];
                    float e = (float)v[2 * jj], dd = (float)v[2 * jj + 1];
                    ov[2 * jj]     = (__bf16)(sc * (cs * e - sn * dd));
                    ov[2 * jj + 1] = (__bf16)(sc * (sn * e + cs * dd));
                }
                __bf16* dst = which ? Kb : Qb;
                *(bf16x8*)(dst + ((size_t)(b * NHEAD + h) * SEQ + l) * HD + d) = ov;
            }
        }
    }
}

// ---------------- causal flash attention ----------------
// LDS-TRAFFIC-OPTIMIZED: 512 blocks, QBLK=128 (4 waves x 32 q-rows). Each kf/vf
// LDS read now feeds TWO MFMAs (2 Q/P fragments in registers) -> LDS issue per
// unit work drops ~45% (the r10 accounting showed LDS issue saturated: ~865cy
// of ds ops per block-iter x 4 blocks ~= the measured 3243cy/iter).
// XCD-pinned (xcd=bid&7, 4 heads/XCD, 2MB KV in L2). Complementary-pair qt
// mapping: idx and idx+32 sum to 34 iters -> balanced CUs, longest first.
// K/V double-buffered reg-staged prefetch, ONE barrier/iter. Swapped QK^T,
// register softmax, T13 defer-max, ones-MFMA row-sum, T5 setprio.
// Fully-masked tiles (waves 0-1 past their diagonal) skip compute entirely.
__global__ __launch_bounds__(256, 2)
void attn_kernel(const __bf16* __restrict__ Q, const __bf16* __restrict__ K,
                 const __bf16* __restrict__ VT, __bf16* __restrict__ O) {
    __shared__ __align__(16) char smem[49152];
    // buf0: K@0 V@8192 | buf1: K@16384 V@24576 | Ps/Os @32768 (16K)
    const int lane = threadIdx.x & 63;
    const int w    = threadIdx.x >> 6;
    const int tid  = threadIdx.x;
    const int hi   = lane >> 4;
    const int lo   = lane & 15;
    char* Ps = smem + 32768 + w * 4096;   // per-wave [32 q][64 j] bf16 swz

    const int bid = blockIdx.x;
    const int xcd = bid & 7;
    const int idx = bid >> 3;             // 0..63 per XCD
    int hl, qt;
    if (idx < 32) { hl = idx & 1;       qt = 15 - (idx >> 1); }   // longest first
    else          { hl = 2 + (idx & 1); qt = (idx - 32) >> 1; }   // complement
    const int bh = xcd * 4 + hl;

    const __bf16* Qbh  = Q  + (size_t)bh * SEQ * HD;
    const __bf16* Kbh  = K  + (size_t)bh * SEQ * HD;
    const __bf16* VTbh = VT + (size_t)bh * HD * SEQ;
    const int b = bh >> 4, h = bh & 15;

    const int nkv  = 2 * qt + 2;          // kv tiles for this q-tile
    const int iBase = qt * 128 + w * 32;  // wave's first q-row

    // prologue: stage tile 0 into buf0 (pre-swizzled source, linear LDS dest)
    #pragma unroll
    for (int c = 0; c < 2; ++c) {
        int id = (c * 4 + w) * 64 + lane;
        int row = id >> 3, cc = id & 7;
        int sw = (cc ^ (row & 7)) << 3;
        gload16(Kbh + (size_t)row * HD + sw, smem + (c * 4 + w) * 1024);
        gload16(VTbh + (size_t)row * SEQ + sw, smem + 8192 + (c * 4 + w) * 1024);
    }

    // two 16-row Q fragments per wave
    bf16x8 qf[2][2];
    #pragma unroll
    for (int f = 0; f < 2; ++f) {
        int qrow = iBase + f * 16 + lo;
        qf[f][0] = *(const bf16x8*)(Qbh + (size_t)qrow * HD + hi * 8);
        qf[f][1] = *(const bf16x8*)(Qbh + (size_t)qrow * HD + 32 + hi * 8);
    }

    bf16x8 ones;
    #pragma unroll
    for (int i = 0; i < 8; ++i) ones[i] = (__bf16)1.0f;

    f32x4 o0[4] = {}, o1[4] = {};
    f32x4 ls0 = {}, ls1 = {};
    float mrow0 = -1e30f, mrow1 = -1e30f;

    int cur = 0;
    __syncthreads();   // drains prologue gload_lds for all waves

    for (int kb = 0; kb < nkv; ++kb) {
        // issue next tile's loads to REGISTERS early (latency hides under compute)
        bf16x8 kreg[2], vreg[2];
        if (kb + 1 < nkv) {
            #pragma unroll
            for (int c = 0; c < 2; ++c) {
                int id = c * 256 + tid;
                int row = id >> 3, cc = id & 7;
                kreg[c] = *(const bf16x8*)(Kbh + (size_t)((kb + 1) * 64 + row) * HD + cc * 8);
                vreg[c] = *(const bf16x8*)(VTbh + (size_t)row * SEQ + (kb + 1) * 64 + cc * 8);
            }
        }

        char* Ks = smem + cur * 16384;
        char* Vs = Ks + 8192;

        // wave-uniform: is this tile entirely above our rows? (fully masked)
        const bool active = (kb * 64) <= (iBase + 31);

        if (active) {
            // swapped QK^T for both fragments: kf read ONCE feeds 2 MFMAs
            f32x4 s0[4], s1[4];
            __builtin_amdgcn_s_setprio(1);
            #pragma unroll
            for (int jt = 0; jt < 4; ++jt) {
                f32x4 z0 = {}, z1 = {};
                #pragma unroll
                for (int ks = 0; ks < 2; ++ks) {
                    int row = jt * 16 + lo;
                    int c = ks * 4 + hi;
                    bf16x8 kf = *(const bf16x8*)(Ks + row * 128 + ((c ^ (row & 7)) << 4));
                    z0 = MFMA16x16(kf, qf[0][ks], z0);
                    z1 = MFMA16x16(kf, qf[1][ks], z1);
                }
                s0[jt] = z0;
                s1[jt] = z1;
            }
            __builtin_amdgcn_s_setprio(0);

            // causal mask (only near the diagonal)
            if (kb * 64 + 63 > iBase) {
                int i0 = iBase + lo, i1 = iBase + 16 + lo;
                #pragma unroll
                for (int jt = 0; jt < 4; ++jt)
                    #pragma unroll
                    for (int rr = 0; rr < 4; ++rr) {
                        int j = kb * 64 + jt * 16 + hi * 4 + rr;
                        if (j > i0) s0[jt][rr] = -1e30f;
                        if (j > i1) s1[jt][rr] = -1e30f;
                    }
            }

            // per-lane partial max per fragment
            float a0 = fmaxf(fmaxf(fmaxf(s0[0][0], s0[0][1]), s0[0][2]), s0[0][3]);
            float a1 = fmaxf(fmaxf(fmaxf(s0[1][0], s0[1][1]), s0[1][2]), s0[1][3]);
            float a2 = fmaxf(fmaxf(fmaxf(s0[2][0], s0[2][1]), s0[2][2]), s0[2][3]);
            float a3 = fmaxf(fmaxf(fmaxf(s0[3][0], s0[3][1]), s0[3][2]), s0[3][3]);
            float pmax0 = fmaxf(fmaxf(a0, a1), fmaxf(a2, a3));
            float b0 = fmaxf(fmaxf(fmaxf(s1[0][0], s1[0][1]), s1[0][2]), s1[0][3]);
            float b1 = fmaxf(fmaxf(fmaxf(s1[1][0], s1[1][1]), s1[1][2]), s1[1][3]);
            float b2 = fmaxf(fmaxf(fmaxf(s1[2][0], s1[2][1]), s1[2][2]), s1[2][3]);
            float b3 = fmaxf(fmaxf(fmaxf(s1[3][0], s1[3][1]), s1[3][2]), s1[3][3]);
            float pmax1 = fmaxf(fmaxf(b0, b1), fmaxf(b2, b3));

            // T13 defer-max (rare path)
            if (!__all(pmax0 <= mrow0 + 8.0f && pmax1 <= mrow1 + 8.0f)) {
                {
                    float pm = fmaxf(pmax0, __shfl_xor(pmax0, 16));
                    pm = fmaxf(pm, __shfl_xor(pm, 32));
                    float mn = fmaxf(mrow0, pm);
                    float alpha = exp2f(mrow0 - mn);
                    mrow0 = mn;
                    float ar[4];
                    #pragma unroll
                    for (int rr = 0; rr < 4; ++rr) ar[rr] = __shfl(alpha, hi * 4 + rr);
                    #pragma unroll
                    for (int rr = 0; rr < 4; ++rr) ls0[rr] *= ar[rr];
                    #pragma unroll
                    for (int dt = 0; dt < 4; ++dt)
                        #pragma unroll
                        for (int rr = 0; rr < 4; ++rr) o0[dt][rr] *= ar[rr];
                }
                {
                    float pm = fmaxf(pmax1, __shfl_xor(pmax1, 16));
                    pm = fmaxf(pm, __shfl_xor(pm, 32));
                    float mn = fmaxf(mrow1, pm);
                    float alpha = exp2f(mrow1 - mn);
                    mrow1 = mn;
                    float ar[4];
                    #pragma unroll
                    for (int rr = 0; rr < 4; ++rr) ar[rr] = __shfl(alpha, hi * 4 + rr);
                    #pragma unroll
                    for (int rr = 0; rr < 4; ++rr) ls1[rr] *= ar[rr];
                    #pragma unroll
                    for (int dt = 0; dt < 4; ++dt)
                        #pragma unroll
                        for (int rr = 0; rr < 4; ++rr) o1[dt][rr] *= ar[rr];
                }
            }

            // exp2 + pack 4 bf16 -> one ds_write_b64 per (frag, jt)
            {
                int swr = (lo & 7) << 4;
                #pragma unroll
                for (int jt = 0; jt < 4; ++jt) {
                    bf16x4 pk;
                    #pragma unroll
                    for (int rr = 0; rr < 4; ++rr)
                        pk[rr] = (__bf16)exp2f(s0[jt][rr] - mrow0);
                    int jj = (jt * 16 + hi * 4) * 2;
                    *(bf16x4*)(Ps + lo * 128 + (jj ^ swr)) = pk;
                }
                #pragma unroll
                for (int jt = 0; jt < 4; ++jt) {
                    bf16x4 pk;
                    #pragma unroll
                    for (int rr = 0; rr < 4; ++rr)
                        pk[rr] = (__bf16)exp2f(s1[jt][rr] - mrow1);
                    int jj = (jt * 16 + hi * 4) * 2;
                    *(bf16x4*)(Ps + (16 + lo) * 128 + (jj ^ swr)) = pk;
                }
            }
        }

        // write prefetched tile into the OTHER buffer (its readers all passed
        // the previous barrier); fills P write->read latency gap
        if (kb + 1 < nkv) {
            char* Kn = smem + (cur ^ 1) * 16384;
            char* Vn = Kn + 8192;
            #pragma unroll
            for (int c = 0; c < 2; ++c) {
                int id = c * 256 + tid;
                int row = id >> 3, cc = id & 7;
                int sw = (cc ^ (row & 7)) << 4;
                *(bf16x8*)(Kn + row * 128 + sw) = kreg[c];
                *(bf16x8*)(Vn + row * 128 + sw) = vreg[c];
            }
        }

        if (active) {
            // PV for both fragments: vf read ONCE feeds 2 MFMAs
            __builtin_amdgcn_s_setprio(1);
            #pragma unroll
            for (int js = 0; js < 2; ++js) {
                int cb = js * 4 + hi;
                int sw = ((cb ^ (lo & 7)) << 4);
                bf16x8 pf0 = *(const bf16x8*)(Ps + lo * 128 + sw);
                bf16x8 pf1 = *(const bf16x8*)(Ps + (16 + lo) * 128 + sw);
                ls0 = MFMA16x16(pf0, ones, ls0);
                ls1 = MFMA16x16(pf1, ones, ls1);
                #pragma unroll
                for (int dt = 0; dt < 4; ++dt) {
                    int vrow = dt * 16 + lo;
                    bf16x8 vf = *(const bf16x8*)(Vs + vrow * 128 + ((cb ^ (vrow & 7)) << 4));
                    o0[dt] = MFMA16x16(pf0, vf, o0[dt]);
                    o1[dt] = MFMA16x16(pf1, vf, o1[dt]);
                }
            }
            __builtin_amdgcn_s_setprio(0);
        }

        __syncthreads();
        cur ^= 1;
    }

    // 1/l directly from ls (accumulator row layout, no shuffles)
    float linv0[4], linv1[4];
    #pragma unroll
    for (int rr = 0; rr < 4; ++rr) { linv0[rr] = 1.0f / ls0[rr]; linv1[rr] = 1.0f / ls1[rr]; }

    // stage O tile [128 q][64 d] into the Ps region (each wave its own 4KB)
    char* Os = smem + 32768;
    #pragma unroll
    for (int dt = 0; dt < 4; ++dt)
        #pragma unroll
        for (int rr = 0; rr < 4; ++rr) {
            int orow0 = w * 32 + hi * 4 + rr;
            int orow1 = orow0 + 16;
            int oc = (dt * 16 + lo) * 2;
            *(__bf16*)(Os + orow0 * 128 + (oc ^ ((orow0 & 7) << 4))) = (__bf16)(o0[dt][rr] * linv0[rr]);
            *(__bf16*)(Os + orow1 * 128 + (oc ^ ((orow1 & 7) << 4))) = (__bf16)(o1[dt][rr] * linv1[rr]);
        }
    __syncthreads();

    #pragma unroll
    for (int c = 0; c < 4; ++c) {
        int id = c * 256 + tid;
        int row = id >> 3, cc = id & 7;
        bf16x8 v = *(const bf16x8*)(Os + row * 128 + ((cc ^ (row & 7)) << 4));
        *(bf16x8*)(O + (size_t)(b * SEQ + qt * 128 + row) * DM + h * HD + cc * 8) = v;
    }
}

extern "C" void kernel_launch(void* const* d_in, const int* in_sizes, int n_in,
                              void* d_out, int out_size, void* d_ws, size_t ws_size,
                              hipStream_t stream) {
    const float* x  = (const float*)d_in[0];
    const float* wq = (const float*)d_in[1];
    const float* wk = (const float*)d_in[2];
    const float* wv = (const float*)d_in[3];
    const float* wo = (const float*)d_in[4];
    const int* tpos = (const int*)d_in[5];
    float* out = (float*)d_out;
    char* ws = (char*)d_ws;

    __bf16* xb   = (__bf16*)(ws);                        // 8 MB  [4096][1024]
    __bf16* wqkv = (__bf16*)(ws + (size_t)(8  << 20));   // 6 MB  [3072][1024]
    __bf16* wob  = (__bf16*)(ws + (size_t)(14 << 20));   // 2 MB  [1024][1024]
    __bf16* Qb   = (__bf16*)(ws + (size_t)(16 << 20));   // 8 MB  [32][2048][64]
    __bf16* Kb   = (__bf16*)(ws + (size_t)(24 << 20));   // 8 MB  [32][2048][64]
    __bf16* VTb  = (__bf16*)(ws + (size_t)(32 << 20));   // 8 MB  [32][64][2048]
    __bf16* Ob   = (__bf16*)(ws + (size_t)(40 << 20));   // 8 MB  [4096][1024]
    float* ct    = (float*)(ws + (size_t)(48 << 20));            // 256 KB
    float* st    = (float*)(ws + (size_t)(48 << 20) + 262144);   // 256 KB

    prep_kernel<<<8448, 256, 0, stream>>>(x, wq, wk, wv, wo, xb, wqkv, wob, ct, st);
    gemm_bt_kernel<0, 128><<<768, 256, 0, stream>>>(xb, wqkv, nullptr, Qb, Kb, VTb,
                                                    tpos, ct, st, 3072, 1024);
    attn_kernel<<<512, 256, 0, stream>>>(Qb, Kb, VTb, Ob);
    gemm_bt_kernel<1, 64><<<512, 256, 0, stream>>>(Ob, wob, out, nullptr, nullptr, nullptr,
                                                   nullptr, nullptr, nullptr, 1024, 1024);
}